// Round 10
// baseline (181.272 us; speedup 1.0000x reference)
//
#include <hip/hip_runtime.h>
#include <hip/hip_bf16.h>
#include <cstdint>
#include <cstddef>
#include <math.h>

// ---------------------------------------------------------------------------
// DecoderAttention on MI355X. Pipeline (r10 = r9 + attn LDS-pipe fix):
//   cvt:    enc,resid f32 -> bf16
//   wtrans: Qs/Ks/Vs/O f32 -> bf16, transposed to [n][k] (WqT|WkT contiguous)
//   gemm_bt<3>: {Q,K} = enc·[Wq|Wk]+b -> [bh][s][64] bf16; Q pre-scaled by
//               0.125*log2(e) (attn scores in log2 units for free)
//   gemm_bt<2>: V = resid·Wv+bv -> [bh][d][s] bf16 (transposed store)
//   attn:   causal flash. r9 diagnosis: LDS-ISSUE-PIPE BOUND (18 b128 + 16
//           b16 per wave-tile ≈ 620cyc vs 80cyc MFMA). r10: 2 waves x 32
//           q-rows/wave — K/V fragment reads shared across 2 q-strips ->
//           0.69x LDS ops per q-row. Grid 128x16 heavy-first, 6 blocks/CU.
//   gemm_bt<0>: out = Z·Wo+bo -> f32
// History: r5 dbuf REGRESSED (occupancy); r6 QKV fusion REGRESSED;
//          r8 launch_bounds(256,6) forced VGPR 40 -> spills REGRESSED.
// ---------------------------------------------------------------------------

typedef __attribute__((ext_vector_type(8))) short short8;
typedef __attribute__((ext_vector_type(4))) short short4v;
typedef __attribute__((ext_vector_type(4))) float f32x4;

#define MFMA16(A, B, C) __builtin_amdgcn_mfma_f32_16x16x32_bf16(A, B, C, 0, 0, 0)

__device__ inline short f2bs(float f) {
    __bf16 h = (__bf16)f;
    return __builtin_bit_cast(short, h);
}

typedef const __attribute__((address_space(1))) unsigned int* as1_u32p;
typedef __attribute__((address_space(3))) unsigned int* as3_u32p;

__device__ inline void gload_lds16(const void* g, void* lds_base) {
    __builtin_amdgcn_global_load_lds((as1_u32p)(uintptr_t)g,
                                     (as3_u32p)(uintptr_t)lds_base, 16, 0, 0);
}

#define ATTN_SC 0.18033688f   /* 0.125 * log2(e) */
#define ATTN_THR 11.5415603f  /* 8 * log2(e) */

// ---------------------------------------------------------------------------
// cvt: f32 -> bf16, 8 elems/thread, grid.y selects tensor (0=enc,1=resid)
// ---------------------------------------------------------------------------
__global__ __launch_bounds__(256) void cvt_k(const float* __restrict__ a,
                                             const float* __restrict__ b,
                                             short* __restrict__ oa,
                                             short* __restrict__ ob) {
    const int n = 8 * 1024 * 1024;
    const float* src = blockIdx.y ? b : a;
    short* dst = blockIdx.y ? ob : oa;
    for (int i = (blockIdx.x * 256 + threadIdx.x) * 8; i < n; i += gridDim.x * 256 * 8) {
        f32x4 v0 = *(const f32x4*)(src + i), v1 = *(const f32x4*)(src + i + 4);
        short8 o;
        o[0] = f2bs(v0[0]); o[1] = f2bs(v0[1]); o[2] = f2bs(v0[2]); o[3] = f2bs(v0[3]);
        o[4] = f2bs(v1[0]); o[5] = f2bs(v1[1]); o[6] = f2bs(v1[2]); o[7] = f2bs(v1[3]);
        *(short8*)(dst + i) = o;
    }
}

// ---------------------------------------------------------------------------
// wtrans: weight transpose+convert (unchanged).
// ---------------------------------------------------------------------------
__global__ __launch_bounds__(256) void wtrans_k(
    const float* __restrict__ Wq, const float* __restrict__ Wk,
    const float* __restrict__ Wv, const float* __restrict__ Wo,
    short* __restrict__ TQ, short* __restrict__ TK,
    short* __restrict__ TV, short* __restrict__ TO) {
    __shared__ short tile[64][72];
    const int wsel = blockIdx.y;
    const float* in = wsel == 0 ? Wq : wsel == 1 ? Wk : wsel == 2 ? Wv : Wo;
    short* out = wsel == 0 ? TQ : wsel == 1 ? TK : wsel == 2 ? TV : TO;
    const int h = blockIdx.x >> 4, tk = blockIdx.x & 15;
    const int t = threadIdx.x;
    size_t ioff; int istr, orow0, ocol0;
    if (wsel < 3) { ioff = (size_t)h * 65536 + (size_t)tk * 64 * 64; istr = 64;   orow0 = h * 64;  ocol0 = tk * 64; }
    else          { ioff = (size_t)h * 65536 + (size_t)tk * 64;      istr = 1024; orow0 = tk * 64; ocol0 = h * 64; }
    {
        const int r = t >> 2, c0 = (t & 3) * 16;
        const float* src = in + ioff + (size_t)r * istr + c0;
#pragma unroll
        for (int j = 0; j < 4; j++) {
            f32x4 v = *(const f32x4*)(src + j * 4);
            tile[r][c0 + j * 4 + 0] = f2bs(v[0]);
            tile[r][c0 + j * 4 + 1] = f2bs(v[1]);
            tile[r][c0 + j * 4 + 2] = f2bs(v[2]);
            tile[r][c0 + j * 4 + 3] = f2bs(v[3]);
        }
    }
    __syncthreads();
    {
        const int cc = t >> 2, rb = (t & 3) * 16;
        short8 o0, o1;
#pragma unroll
        for (int j = 0; j < 8; j++) { o0[j] = tile[rb + j][cc]; o1[j] = tile[rb + 8 + j][cc]; }
        short* dst = out + (size_t)(orow0 + cc) * 1024 + ocol0 + rb;
        *(short8*)dst = o0;
        *(short8*)(dst + 8) = o1;
    }
}

// ---------------------------------------------------------------------------
// GEMM: 128x128 tile, BK=64, global_load_lds + involution swizzle.
//   MODE 0: f32 out row-major [8192][1024]
//   MODE 2: bf16 out [bh][d][s]  (V, transposed, packed 8B stores)
//   MODE 3: dual bf16 out [bh][s][64]: cols<1024 -> Cp/bias (Q, pre-scaled by
//           ATTN_SC), else Cp2/bias2 (K). B=[WqT|WkT] is [2048][1024], grid.y=16
// ---------------------------------------------------------------------------
template <int MODE>
__global__ __launch_bounds__(256) void gemm_bt(const short* __restrict__ A,
                                               const short* __restrict__ B,
                                               const float* __restrict__ bias,
                                               void* __restrict__ Cp,
                                               const float* __restrict__ bias2,
                                               void* __restrict__ Cp2) {
    constexpr int K = 1024;
    __shared__ short As[128 * 64];
    __shared__ short Bs[128 * 64];
    const int t = threadIdx.x, l = t & 63, w = t >> 6, lr = l & 15, lg = l >> 4;
    const int wm = (w >> 1) * 64, wn = (w & 1) * 64;
    const int m0 = blockIdx.x * 128, n0 = blockIdx.y * 128;
    const int sr = l >> 3, cb = l & 7;
    f32x4 acc[4][4] = {};

    for (int k0 = 0; k0 < K; k0 += 64) {
#pragma unroll
        for (int i = 0; i < 4; i++) {
            const int c = w * 4 + i, r = c * 8 + sr, cbs = cb ^ (r & 7);
            gload_lds16(A + (size_t)(m0 + r) * K + k0 + cbs * 8, &As[c * 512]);
        }
#pragma unroll
        for (int i = 0; i < 4; i++) {
            const int c = w * 4 + i, r = c * 8 + sr, cbs = cb ^ (r & 7);
            gload_lds16(B + (size_t)(n0 + r) * K + k0 + cbs * 8, &Bs[c * 512]);
        }
        __syncthreads();
#pragma unroll
        for (int kk = 0; kk < 2; kk++) {
            short8 af[4], bf[4];
#pragma unroll
            for (int mi = 0; mi < 4; mi++) {
                const int r = wm + mi * 16 + lr;
                af[mi] = *(const short8*)&As[r * 64 + ((kk * 4 + lg) ^ (r & 7)) * 8];
            }
#pragma unroll
            for (int nj = 0; nj < 4; nj++) {
                const int r = wn + nj * 16 + lr;
                bf[nj] = *(const short8*)&Bs[r * 64 + ((kk * 4 + lg) ^ (r & 7)) * 8];
            }
#pragma unroll
            for (int mi = 0; mi < 4; mi++)
#pragma unroll
                for (int nj = 0; nj < 4; nj++)
                    acc[mi][nj] = MFMA16(af[mi], bf[nj], acc[mi][nj]);
        }
        __syncthreads();
    }

#pragma unroll
    for (int mi = 0; mi < 4; mi++) {
#pragma unroll
        for (int nj = 0; nj < 4; nj++) {
            const int col = n0 + wn + nj * 16 + lr;
            if (MODE == 3) {
                const int h2 = col >> 6;  // 0..31
                short* dst = (short*)(h2 < 16 ? Cp : Cp2);
                const float bv = h2 < 16 ? bias[col & 1023] : bias2[col & 1023];
                const float sc = h2 < 16 ? ATTN_SC : 1.0f;  // pre-scale Q only
                const int h = h2 & 15, d = col & 63;
#pragma unroll
                for (int e = 0; e < 4; e++) {
                    const int row = m0 + wm + mi * 16 + lg * 4 + e;
                    const int bb = row >> 10, s = row & 1023;
                    dst[((size_t)(bb * 16 + h) * 1024 + s) * 64 + d] =
                        f2bs((acc[mi][nj][e] + bv) * sc);
                }
            } else if (MODE == 2) {
                const float bv = bias[col];
                const int rowb = m0 + wm + mi * 16 + lg * 4;
                const int bb = rowb >> 10, s0 = rowb & 1023;
                const int h = col >> 6, d = col & 63;
                short4v pk;
#pragma unroll
                for (int e = 0; e < 4; e++) pk[e] = f2bs(acc[mi][nj][e] + bv);
                *(short4v*)((short*)Cp + ((size_t)(bb * 16 + h) * 64 + d) * 1024 + s0) = pk;
            } else {
                const float bv = bias[col];
#pragma unroll
                for (int e = 0; e < 4; e++) {
                    const int row = m0 + wm + mi * 16 + lg * 4 + e;
                    ((float*)Cp)[(size_t)row * 1024 + col] = acc[mi][nj][e] + bv;
                }
            }
        }
    }
}

// ---------------------------------------------------------------------------
// Causal flash attention (r10: 2 waves x 32 q-rows, shared K/V fragments).
//   Q: bf16 [bh][s][64], PRE-SCALED by 0.125*log2e; K: bf16 [bh][s][64];
//   V: bf16 [bh][d][s]; Z: bf16 [b*1024+s][h*64+d]
// Grid (128 bh, 16), qb = 15-y; 64 q-rows per block as 2 waves x 2 strips.
// Per wave-tile: 8 kf + 8 vf b128 reads shared across both strips.
// ---------------------------------------------------------------------------
template <bool DIAG>
__device__ __forceinline__ void attn_tile2(
    const short* __restrict__ Ks, const short* __restrict__ Vt,
    short (*__restrict__ Psw)[76],
    const short8 (*__restrict__ qf)[2], float (*__restrict__ m)[4],
    float (*__restrict__ ps)[4], f32x4 (*__restrict__ acc)[4],
    int lr, int lg, int rowbase) {
    // ---- S = Q·K^T for both strips, kf shared ----
    f32x4 sf[2][4];
#pragma unroll
    for (int n = 0; n < 4; n++) {
        const int rk = n * 16 + lr;
        short8 kf0 = *(const short8*)&Ks[rk * 64 + ((lg) ^ (rk & 7)) * 8];
        short8 kf1 = *(const short8*)&Ks[rk * 64 + ((4 + lg) ^ (rk & 7)) * 8];
#pragma unroll
        for (int s = 0; s < 2; s++) {
            f32x4 a = {};
            a = MFMA16(qf[s][0], kf0, a);
            a = MFMA16(qf[s][1], kf1, a);
            sf[s][n] = a;
        }
    }
    // ---- per-strip softmax ----
#pragma unroll
    for (int s = 0; s < 2; s++) {
        const int rowloc = rowbase + s * 16 + lg * 4;
        if (DIAG) {
#pragma unroll
            for (int n = 0; n < 4; n++)
#pragma unroll
                for (int e = 0; e < 4; e++)
                    if (n * 16 + lr > rowloc + e) sf[s][n][e] = -1e30f;
        }
        float pm[4];
#pragma unroll
        for (int e = 0; e < 4; e++)
            pm[e] = fmaxf(fmaxf(sf[s][0][e], sf[s][1][e]),
                          fmaxf(sf[s][2][e], sf[s][3][e]));
        bool ok = true;
#pragma unroll
        for (int e = 0; e < 4; e++) ok = ok && (pm[e] <= m[s][e] + ATTN_THR);
        if (!__all(ok)) {
#pragma unroll
            for (int e = 0; e < 4; e++) {
                float tm = pm[e];
#pragma unroll
                for (int off = 1; off < 16; off <<= 1)
                    tm = fmaxf(tm, __shfl_xor(tm, off));
                float nm = fmaxf(m[s][e], tm);
                float al = exp2f(m[s][e] - nm);
                m[s][e] = nm;
                ps[s][e] *= al;
#pragma unroll
                for (int n4 = 0; n4 < 4; n4++) acc[s][n4][e] *= al;
            }
        }
#pragma unroll
        for (int e = 0; e < 4; e++) {
#pragma unroll
            for (int n = 0; n < 4; n++) {
                float p = exp2f(sf[s][n][e] - m[s][e]);
                ps[s][e] += p;
                Psw[s * 16 + lg * 4 + e][n * 16 + lr] = f2bs(p);
            }
        }
    }
    // ---- O += P·V, vf shared across strips ----
#pragma unroll
    for (int c = 0; c < 2; c++) {
        short8 pf0 = *(const short8*)&Psw[lr][lg * 8 + c * 32];
        short8 pf1 = *(const short8*)&Psw[16 + lr][lg * 8 + c * 32];
#pragma unroll
        for (int n4 = 0; n4 < 4; n4++) {
            const int rv = n4 * 16 + lr;
            short8 vf = *(const short8*)&Vt[rv * 64 + ((lg + 4 * c) ^ (rv & 7)) * 8];
            acc[0][n4] = MFMA16(pf0, vf, acc[0][n4]);
            acc[1][n4] = MFMA16(pf1, vf, acc[1][n4]);
        }
    }
}

__global__ __launch_bounds__(128, 3) void attn_k(const short* __restrict__ Q,
                                                 const short* __restrict__ Kp,
                                                 const short* __restrict__ Vg,
                                                 short* __restrict__ Z) {
    __shared__ short Ks[64 * 64];
    __shared__ short Vt[64 * 64];
    __shared__ short Ps[2][32][76];
    const int t = threadIdx.x, l = t & 63, w = t >> 6, lr = l & 15, lg = l >> 4;
    const int bh = blockIdx.x;
    const int qb = 15 - blockIdx.y;          // heavy blocks dispatch first
    const int q0 = qb * 64;
    const size_t base = (size_t)bh * 65536;
    const int sr = l >> 3, cb = l & 7;
    const int rowbase = w * 32;

    short8 qf[2][2];
#pragma unroll
    for (int s = 0; s < 2; s++) {
        const short* qp = Q + base + (size_t)(q0 + w * 32 + s * 16 + lr) * 64 + lg * 8;
        qf[s][0] = *(const short8*)qp;
        qf[s][1] = *(const short8*)(qp + 32);
    }

    float m[2][4], ps[2][4];
    f32x4 acc[2][4] = {};
#pragma unroll
    for (int s = 0; s < 2; s++)
#pragma unroll
        for (int e = 0; e < 4; e++) { m[s][e] = -1e30f; ps[s][e] = 0.f; }

    for (int kt = 0; kt <= qb; kt++) {
        const int k0 = kt * 64;
#pragma unroll
        for (int i = 0; i < 4; i++) {
            const int c = w * 4 + i, r = c * 8 + sr, cbs = cb ^ (r & 7);
            gload_lds16(Kp + base + (size_t)(k0 + r) * 64 + cbs * 8, &Ks[c * 512]);
            gload_lds16(Vg + base + (size_t)r * 1024 + k0 + cbs * 8, &Vt[c * 512]);
        }
        __syncthreads();
        if (kt == qb)
            attn_tile2<true>(Ks, Vt, Ps[w], qf, m, ps, acc, lr, lg, rowbase);
        else
            attn_tile2<false>(Ks, Vt, Ps[w], qf, m, ps, acc, lr, lg, rowbase);
        __syncthreads();
    }

    // ---- epilogue: denom reduce (once) + normalize + store ----
    const int b = bh >> 4, h = bh & 15;
#pragma unroll
    for (int s = 0; s < 2; s++) {
#pragma unroll
        for (int e = 0; e < 4; e++) {
            float sv = ps[s][e];
#pragma unroll
            for (int off = 1; off < 16; off <<= 1) sv += __shfl_xor(sv, off);
            ps[s][e] = 1.f / sv;
        }
#pragma unroll
        for (int n4 = 0; n4 < 4; n4++)
#pragma unroll
            for (int e = 0; e < 4; e++) {
                const int row = q0 + w * 32 + s * 16 + lg * 4 + e;
                Z[((size_t)(b * 1024 + row)) * 1024 + h * 64 + n4 * 16 + lr] =
                    f2bs(acc[s][n4][e] * ps[s][e]);
            }
    }
}

// ---------------------------------------------------------------------------
extern "C" void kernel_launch(void* const* d_in, const int* in_sizes, int n_in,
                              void* d_out, int out_size, void* d_ws, size_t ws_size,
                              hipStream_t stream) {
    const float* resid = (const float*)d_in[0];
    const float* enc   = (const float*)d_in[1];
    const float* Qs    = (const float*)d_in[2];
    const float* Qbs   = (const float*)d_in[3];
    const float* Ksw   = (const float*)d_in[4];
    const float* Kbs   = (const float*)d_in[5];
    const float* Vs    = (const float*)d_in[6];
    const float* Vbs   = (const float*)d_in[7];
    const float* Ow    = (const float*)d_in[8];
    const float* Ob    = (const float*)d_in[9];
    float* out = (float*)d_out;

    char* ws = (char*)d_ws;
    const size_t M16 = (size_t)16 * 1024 * 1024;
    short* Aenc = (short*)ws;               // aliased as Zw after QK-GEMM
    short* Ares = (short*)(ws + M16);
    short* Qw   = (short*)(ws + 2 * M16);
    short* Kw   = (short*)(ws + 3 * M16);
    short* Vw   = (short*)(ws + 4 * M16);   // [bh][d][s]
    short* WqT  = (short*)(ws + 5 * M16);                       // [1024][1024]
    short* WkT  = (short*)(ws + 5 * M16 + 2 * 1024 * 1024);     // contiguous after WqT
    short* WvT  = (short*)(ws + 5 * M16 + 4 * 1024 * 1024);
    short* WoT  = (short*)(ws + 5 * M16 + 6 * 1024 * 1024);
    short* Zw   = Aenc;

    cvt_k<<<dim3(2048, 2), 256, 0, stream>>>(enc, resid, Aenc, Ares);
    wtrans_k<<<dim3(256, 4), 256, 0, stream>>>(Qs, Ksw, Vs, Ow, WqT, WkT, WvT, WoT);
    gemm_bt<3><<<dim3(64, 16), 256, 0, stream>>>(Aenc, WqT, Qbs, Qw, Kbs, Kw);
    gemm_bt<2><<<dim3(64, 8), 256, 0, stream>>>(Ares, WvT, Vbs, Vw, nullptr, nullptr);
    attn_k<<<dim3(128, 16), 128, 0, stream>>>(Qw, Kw, Vw, Zw);
    gemm_bt<0><<<dim3(64, 8), 256, 0, stream>>>(Zw, WoT, Ob, out, nullptr, nullptr);
}

// Round 11
// 160.544 us; speedup vs baseline: 1.1291x; 1.1291x over previous
//
#include <hip/hip_runtime.h>
#include <hip/hip_bf16.h>
#include <cstdint>
#include <cstddef>
#include <math.h>

// ---------------------------------------------------------------------------
// DecoderAttention on MI355X. Pipeline (r11 = r9 projections + r4 attention):
//   cvt:    enc,resid f32 -> bf16
//   wtrans: Qs/Ks/Vs/O f32 -> bf16, transposed to [n][k] (WqT|WkT contiguous)
//   gemm_bt<3>: {Q,K} = enc·[Wq|Wk]+b -> [bh][s][64] bf16; Q pre-scaled by
//               0.125*log2(e)
//   gemm_bt<2>: V = resid·Wv+bv -> [bh][d][s] bf16 (transposed store)
//   attn:   r4 kernel (best measured, 59.5us): paired q-tiles {y,15-y},
//           Ps[4][16][72] (16B-aligned rows; r5's [76] pad broke b128
//           alignment and cost +14%), defer-max, deferred denom.
//   gemm_bt<0>: out = Z·Wo+bo -> f32
// Failed-experiment ledger: r5 dbuf (occupancy loss); r6 QKV 3-way fusion;
//   r8 launch_bounds(256,6) spills; r5 Ps[76] pad (alignment); r10 2-wave
//   strip sharing (spills + occupancy). All reverted.
// ---------------------------------------------------------------------------

typedef __attribute__((ext_vector_type(8))) short short8;
typedef __attribute__((ext_vector_type(4))) short short4v;
typedef __attribute__((ext_vector_type(4))) float f32x4;

#define MFMA16(A, B, C) __builtin_amdgcn_mfma_f32_16x16x32_bf16(A, B, C, 0, 0, 0)

__device__ inline short f2bs(float f) {
    __bf16 h = (__bf16)f;
    return __builtin_bit_cast(short, h);
}

typedef const __attribute__((address_space(1))) unsigned int* as1_u32p;
typedef __attribute__((address_space(3))) unsigned int* as3_u32p;

__device__ inline void gload_lds16(const void* g, void* lds_base) {
    __builtin_amdgcn_global_load_lds((as1_u32p)(uintptr_t)g,
                                     (as3_u32p)(uintptr_t)lds_base, 16, 0, 0);
}

#define ATTN_SC 0.18033688f   /* 0.125 * log2(e) */
#define ATTN_THR 11.5415603f  /* 8 * log2(e) */

// ---------------------------------------------------------------------------
// cvt: f32 -> bf16, 8 elems/thread, grid.y selects tensor (0=enc,1=resid)
// ---------------------------------------------------------------------------
__global__ __launch_bounds__(256) void cvt_k(const float* __restrict__ a,
                                             const float* __restrict__ b,
                                             short* __restrict__ oa,
                                             short* __restrict__ ob) {
    const int n = 8 * 1024 * 1024;
    const float* src = blockIdx.y ? b : a;
    short* dst = blockIdx.y ? ob : oa;
    for (int i = (blockIdx.x * 256 + threadIdx.x) * 8; i < n; i += gridDim.x * 256 * 8) {
        f32x4 v0 = *(const f32x4*)(src + i), v1 = *(const f32x4*)(src + i + 4);
        short8 o;
        o[0] = f2bs(v0[0]); o[1] = f2bs(v0[1]); o[2] = f2bs(v0[2]); o[3] = f2bs(v0[3]);
        o[4] = f2bs(v1[0]); o[5] = f2bs(v1[1]); o[6] = f2bs(v1[2]); o[7] = f2bs(v1[3]);
        *(short8*)(dst + i) = o;
    }
}

// ---------------------------------------------------------------------------
// wtrans: weight transpose+convert (unchanged).
// ---------------------------------------------------------------------------
__global__ __launch_bounds__(256) void wtrans_k(
    const float* __restrict__ Wq, const float* __restrict__ Wk,
    const float* __restrict__ Wv, const float* __restrict__ Wo,
    short* __restrict__ TQ, short* __restrict__ TK,
    short* __restrict__ TV, short* __restrict__ TO) {
    __shared__ short tile[64][72];
    const int wsel = blockIdx.y;
    const float* in = wsel == 0 ? Wq : wsel == 1 ? Wk : wsel == 2 ? Wv : Wo;
    short* out = wsel == 0 ? TQ : wsel == 1 ? TK : wsel == 2 ? TV : TO;
    const int h = blockIdx.x >> 4, tk = blockIdx.x & 15;
    const int t = threadIdx.x;
    size_t ioff; int istr, orow0, ocol0;
    if (wsel < 3) { ioff = (size_t)h * 65536 + (size_t)tk * 64 * 64; istr = 64;   orow0 = h * 64;  ocol0 = tk * 64; }
    else          { ioff = (size_t)h * 65536 + (size_t)tk * 64;      istr = 1024; orow0 = tk * 64; ocol0 = h * 64; }
    {
        const int r = t >> 2, c0 = (t & 3) * 16;
        const float* src = in + ioff + (size_t)r * istr + c0;
#pragma unroll
        for (int j = 0; j < 4; j++) {
            f32x4 v = *(const f32x4*)(src + j * 4);
            tile[r][c0 + j * 4 + 0] = f2bs(v[0]);
            tile[r][c0 + j * 4 + 1] = f2bs(v[1]);
            tile[r][c0 + j * 4 + 2] = f2bs(v[2]);
            tile[r][c0 + j * 4 + 3] = f2bs(v[3]);
        }
    }
    __syncthreads();
    {
        const int cc = t >> 2, rb = (t & 3) * 16;
        short8 o0, o1;
#pragma unroll
        for (int j = 0; j < 8; j++) { o0[j] = tile[rb + j][cc]; o1[j] = tile[rb + 8 + j][cc]; }
        short* dst = out + (size_t)(orow0 + cc) * 1024 + ocol0 + rb;
        *(short8*)dst = o0;
        *(short8*)(dst + 8) = o1;
    }
}

// ---------------------------------------------------------------------------
// GEMM: 128x128 tile, BK=64, global_load_lds + involution swizzle.
//   MODE 0: f32 out row-major [8192][1024]
//   MODE 2: bf16 out [bh][d][s]  (V, transposed, packed 8B stores)
//   MODE 3: dual bf16 out [bh][s][64]: cols<1024 -> Cp/bias (Q, pre-scaled by
//           ATTN_SC), else Cp2/bias2 (K). B=[WqT|WkT] is [2048][1024], grid.y=16
// ---------------------------------------------------------------------------
template <int MODE>
__global__ __launch_bounds__(256) void gemm_bt(const short* __restrict__ A,
                                               const short* __restrict__ B,
                                               const float* __restrict__ bias,
                                               void* __restrict__ Cp,
                                               const float* __restrict__ bias2,
                                               void* __restrict__ Cp2) {
    constexpr int K = 1024;
    __shared__ short As[128 * 64];
    __shared__ short Bs[128 * 64];
    const int t = threadIdx.x, l = t & 63, w = t >> 6, lr = l & 15, lg = l >> 4;
    const int wm = (w >> 1) * 64, wn = (w & 1) * 64;
    const int m0 = blockIdx.x * 128, n0 = blockIdx.y * 128;
    const int sr = l >> 3, cb = l & 7;
    f32x4 acc[4][4] = {};

    for (int k0 = 0; k0 < K; k0 += 64) {
#pragma unroll
        for (int i = 0; i < 4; i++) {
            const int c = w * 4 + i, r = c * 8 + sr, cbs = cb ^ (r & 7);
            gload_lds16(A + (size_t)(m0 + r) * K + k0 + cbs * 8, &As[c * 512]);
        }
#pragma unroll
        for (int i = 0; i < 4; i++) {
            const int c = w * 4 + i, r = c * 8 + sr, cbs = cb ^ (r & 7);
            gload_lds16(B + (size_t)(n0 + r) * K + k0 + cbs * 8, &Bs[c * 512]);
        }
        __syncthreads();
#pragma unroll
        for (int kk = 0; kk < 2; kk++) {
            short8 af[4], bf[4];
#pragma unroll
            for (int mi = 0; mi < 4; mi++) {
                const int r = wm + mi * 16 + lr;
                af[mi] = *(const short8*)&As[r * 64 + ((kk * 4 + lg) ^ (r & 7)) * 8];
            }
#pragma unroll
            for (int nj = 0; nj < 4; nj++) {
                const int r = wn + nj * 16 + lr;
                bf[nj] = *(const short8*)&Bs[r * 64 + ((kk * 4 + lg) ^ (r & 7)) * 8];
            }
#pragma unroll
            for (int mi = 0; mi < 4; mi++)
#pragma unroll
                for (int nj = 0; nj < 4; nj++)
                    acc[mi][nj] = MFMA16(af[mi], bf[nj], acc[mi][nj]);
        }
        __syncthreads();
    }

#pragma unroll
    for (int mi = 0; mi < 4; mi++) {
#pragma unroll
        for (int nj = 0; nj < 4; nj++) {
            const int col = n0 + wn + nj * 16 + lr;
            if (MODE == 3) {
                const int h2 = col >> 6;  // 0..31
                short* dst = (short*)(h2 < 16 ? Cp : Cp2);
                const float bv = h2 < 16 ? bias[col & 1023] : bias2[col & 1023];
                const float sc = h2 < 16 ? ATTN_SC : 1.0f;  // pre-scale Q only
                const int h = h2 & 15, d = col & 63;
#pragma unroll
                for (int e = 0; e < 4; e++) {
                    const int row = m0 + wm + mi * 16 + lg * 4 + e;
                    const int bb = row >> 10, s = row & 1023;
                    dst[((size_t)(bb * 16 + h) * 1024 + s) * 64 + d] =
                        f2bs((acc[mi][nj][e] + bv) * sc);
                }
            } else if (MODE == 2) {
                const float bv = bias[col];
                const int rowb = m0 + wm + mi * 16 + lg * 4;
                const int bb = rowb >> 10, s0 = rowb & 1023;
                const int h = col >> 6, d = col & 63;
                short4v pk;
#pragma unroll
                for (int e = 0; e < 4; e++) pk[e] = f2bs(acc[mi][nj][e] + bv);
                *(short4v*)((short*)Cp + ((size_t)(bb * 16 + h) * 64 + d) * 1024 + s0) = pk;
            } else {
                const float bv = bias[col];
#pragma unroll
                for (int e = 0; e < 4; e++) {
                    const int row = m0 + wm + mi * 16 + lg * 4 + e;
                    ((float*)Cp)[(size_t)row * 1024 + col] = acc[mi][nj][e] + bv;
                }
            }
        }
    }
}

// ---------------------------------------------------------------------------
// Causal flash attention — r4 kernel (best measured: 59.5us), Q pre-scaled.
//   Q: bf16 [bh][s][64] (pre-scaled by 0.125*log2e); K: bf16 [bh][s][64];
//   V: bf16 [bh][d][s]; Z: bf16 [b*1024+s][h*64+d]
// 256 thr / 4 waves. Block y handles q-tiles qbA=y (y+1 kt) and qbB=15-y
// (16-y kt) -> uniform 17 tile-computes/block; K/V staged once per kt.
// Ps[4][16][72]: 144B row stride keeps 16B alignment for b128 P-reads
// (Ps[76] = 152B broke alignment, +14% — r5/r7 lesson). Defer-max softmax;
// per-lane partial sums reduced once in epilogue.
// ---------------------------------------------------------------------------
__device__ __forceinline__ void attn_tile(
    const short* __restrict__ Ks, const short* __restrict__ Vt,
    short (*__restrict__ Psw)[72],
    const short8* __restrict__ qf, float* __restrict__ m,
    float* __restrict__ ps, f32x4* __restrict__ acc,
    bool diag, int lr, int lg, int rowloc) {
    f32x4 sf[4];
#pragma unroll
    for (int n = 0; n < 4; n++) {
        const int rk = n * 16 + lr;
        short8 kf0 = *(const short8*)&Ks[rk * 64 + ((lg) ^ (rk & 7)) * 8];
        short8 kf1 = *(const short8*)&Ks[rk * 64 + ((4 + lg) ^ (rk & 7)) * 8];
        f32x4 s = {};
        s = MFMA16(qf[0], kf0, s);
        s = MFMA16(qf[1], kf1, s);
        sf[n] = s;
    }
    if (diag) {
#pragma unroll
        for (int n = 0; n < 4; n++)
#pragma unroll
            for (int e = 0; e < 4; e++)
                if (n * 16 + lr > rowloc + e) sf[n][e] = -1e30f;
    }
    float pm[4];
#pragma unroll
    for (int e = 0; e < 4; e++)
        pm[e] = fmaxf(fmaxf(sf[0][e], sf[1][e]), fmaxf(sf[2][e], sf[3][e]));
    bool ok = true;
#pragma unroll
    for (int e = 0; e < 4; e++) ok = ok && (pm[e] <= m[e] + ATTN_THR);
    if (!__all(ok)) {
#pragma unroll
        for (int e = 0; e < 4; e++) {
            float tm = pm[e];
#pragma unroll
            for (int off = 1; off < 16; off <<= 1)
                tm = fmaxf(tm, __shfl_xor(tm, off));
            float nm = fmaxf(m[e], tm);
            float al = exp2f(m[e] - nm);
            m[e] = nm;
            ps[e] *= al;
#pragma unroll
            for (int n4 = 0; n4 < 4; n4++) acc[n4][e] *= al;
        }
    }
#pragma unroll
    for (int e = 0; e < 4; e++) {
#pragma unroll
        for (int n = 0; n < 4; n++) {
            float p = exp2f(sf[n][e] - m[e]);
            ps[e] += p;
            Psw[lg * 4 + e][n * 16 + lr] = f2bs(p);
        }
    }
#pragma unroll
    for (int c = 0; c < 2; c++) {
        short8 pf = *(const short8*)&Psw[lr][lg * 8 + c * 32];
#pragma unroll
        for (int n4 = 0; n4 < 4; n4++) {
            const int rv = n4 * 16 + lr;
            short8 vf = *(const short8*)&Vt[rv * 64 + ((lg + 4 * c) ^ (rv & 7)) * 8];
            acc[n4] = MFMA16(pf, vf, acc[n4]);
        }
    }
}

__global__ __launch_bounds__(256, 4) void attn_k(const short* __restrict__ Q,
                                                 const short* __restrict__ Kp,
                                                 const short* __restrict__ Vg,
                                                 short* __restrict__ Z) {
    __shared__ short Ks[64 * 64];
    __shared__ short Vt[64 * 64];
    __shared__ short Ps[4][16][72];
    const int t = threadIdx.x, l = t & 63, w = t >> 6, lr = l & 15, lg = l >> 4;
    const int bh = blockIdx.x;
    const int qbA = blockIdx.y, qbB = 15 - qbA;  // qbA 0..7, qbB 8..15
    const int q0A = qbA * 64, q0B = qbB * 64;
    const size_t base = (size_t)bh * 65536;
    const int sr = l >> 3, cb = l & 7;
    const int rowloc = w * 16 + lg * 4;

    short8 qfA[2], qfB[2];
    {
        const short* qp = Q + base + (size_t)(q0A + w * 16 + lr) * 64 + lg * 8;
        qfA[0] = *(const short8*)qp;
        qfA[1] = *(const short8*)(qp + 32);
        qp = Q + base + (size_t)(q0B + w * 16 + lr) * 64 + lg * 8;
        qfB[0] = *(const short8*)qp;
        qfB[1] = *(const short8*)(qp + 32);
    }

    float mA[4], mB[4], psA[4], psB[4];
    f32x4 accA[4] = {}, accB[4] = {};
#pragma unroll
    for (int e = 0; e < 4; e++) { mA[e] = mB[e] = -1e30f; psA[e] = psB[e] = 0.f; }

    for (int kt = 0; kt <= qbB; kt++) {
        const int k0 = kt * 64;
#pragma unroll
        for (int i = 0; i < 2; i++) {
            const int c = w * 2 + i, r = c * 8 + sr, cbs = cb ^ (r & 7);
            gload_lds16(Kp + base + (size_t)(k0 + r) * 64 + cbs * 8, &Ks[c * 512]);
            gload_lds16(Vg + base + (size_t)r * 1024 + k0 + cbs * 8, &Vt[c * 512]);
        }
        __syncthreads();
        if (kt <= qbA)
            attn_tile(Ks, Vt, Ps[w], qfA, mA, psA, accA, kt == qbA, lr, lg, rowloc);
        attn_tile(Ks, Vt, Ps[w], qfB, mB, psB, accB, kt == qbB, lr, lg, rowloc);
        __syncthreads();
    }

    // ---- epilogue: denom reduce (once) + normalize + store both tiles ----
    const int b = bh >> 4, h = bh & 15;
#pragma unroll
    for (int e = 0; e < 4; e++) {
        float sA = psA[e], sB = psB[e];
#pragma unroll
        for (int off = 1; off < 16; off <<= 1) {
            sA += __shfl_xor(sA, off);
            sB += __shfl_xor(sB, off);
        }
        psA[e] = 1.f / sA;
        psB[e] = 1.f / sB;
    }
#pragma unroll
    for (int n4 = 0; n4 < 4; n4++)
#pragma unroll
        for (int e = 0; e < 4; e++) {
            const int rloc = w * 16 + lg * 4 + e;
            Z[((size_t)(b * 1024 + q0A + rloc)) * 1024 + h * 64 + n4 * 16 + lr] =
                f2bs(accA[n4][e] * psA[e]);
            Z[((size_t)(b * 1024 + q0B + rloc)) * 1024 + h * 64 + n4 * 16 + lr] =
                f2bs(accB[n4][e] * psB[e]);
        }
}

// ---------------------------------------------------------------------------
extern "C" void kernel_launch(void* const* d_in, const int* in_sizes, int n_in,
                              void* d_out, int out_size, void* d_ws, size_t ws_size,
                              hipStream_t stream) {
    const float* resid = (const float*)d_in[0];
    const float* enc   = (const float*)d_in[1];
    const float* Qs    = (const float*)d_in[2];
    const float* Qbs   = (const float*)d_in[3];
    const float* Ksw   = (const float*)d_in[4];
    const float* Kbs   = (const float*)d_in[5];
    const float* Vs    = (const float*)d_in[6];
    const float* Vbs   = (const float*)d_in[7];
    const float* Ow    = (const float*)d_in[8];
    const float* Ob    = (const float*)d_in[9];
    float* out = (float*)d_out;

    char* ws = (char*)d_ws;
    const size_t M16 = (size_t)16 * 1024 * 1024;
    short* Aenc = (short*)ws;               // aliased as Zw after QK-GEMM
    short* Ares = (short*)(ws + M16);
    short* Qw   = (short*)(ws + 2 * M16);
    short* Kw   = (short*)(ws + 3 * M16);
    short* Vw   = (short*)(ws + 4 * M16);   // [bh][d][s]
    short* WqT  = (short*)(ws + 5 * M16);                       // [1024][1024]
    short* WkT  = (short*)(ws + 5 * M16 + 2 * 1024 * 1024);     // contiguous after WqT
    short* WvT  = (short*)(ws + 5 * M16 + 4 * 1024 * 1024);
    short* WoT  = (short*)(ws + 5 * M16 + 6 * 1024 * 1024);
    short* Zw   = Aenc;

    cvt_k<<<dim3(2048, 2), 256, 0, stream>>>(enc, resid, Aenc, Ares);
    wtrans_k<<<dim3(256, 4), 256, 0, stream>>>(Qs, Ksw, Vs, Ow, WqT, WkT, WvT, WoT);
    gemm_bt<3><<<dim3(64, 16), 256, 0, stream>>>(Aenc, WqT, Qbs, Qw, Kbs, Kw);
    gemm_bt<2><<<dim3(64, 8), 256, 0, stream>>>(Ares, WvT, Vbs, Vw, nullptr, nullptr);
    attn_k<<<dim3(128, 8), 256, 0, stream>>>(Qw, Kw, Vw, Zw);
    gemm_bt<0><<<dim3(64, 8), 256, 0, stream>>>(Zw, WoT, Ob, out, nullptr, nullptr);
}